// Round 1
// baseline (130.282 us; speedup 1.0000x reference)
//
#include <hip/hip_runtime.h>
#include <hip/hip_bf16.h>

#define EPSV 2.220446049250313e-16f

// Geometry constants
// batch: (8,1,32,32,32) f32 ; preds: (8,6,32,32,32) f32 ; out: (8,) f32
// PAD=3, WIN=7, dist(off)=exp(-d2/16) if d2<16 else 0, w=exp(-(dI)^2/100)*dist

__global__ __launch_bounds__(256) void ncut_main(const float* __restrict__ batch,
                                                 const float* __restrict__ preds,
                                                 float* __restrict__ wsA,
                                                 float* __restrict__ wsV) {
    constexpr int LS = 44;            // LDS row stride (floats): 176B, 16B-aligned, bank-spread
    constexpr int PLANE = 38 * LS;    // one padded (h,w) slice
    __shared__ float bS[PLANE];
    __shared__ float pS[6 * PLANE];
    __shared__ float distS[343];
    __shared__ float redBuf[4][12];

    const int tid = threadIdx.x;
    const int b = blockIdx.x >> 5;    // 8 batches
    const int d = blockIdx.x & 31;    // 32 d-slices
    const int h = tid >> 3;           // 0..31 (row)
    const int w0 = (tid & 7) << 2;    // 0,4,...,28 (4 voxels per thread)

    // spatial Gaussian table: index dz*49 + dy*7 + dx
    for (int i = tid; i < 343; i += 256) {
        int dz = i / 49, r = i - dz * 49;
        int dy = r / 7, dx = r - dy * 7;
        int d2 = (dz - 3) * (dz - 3) + (dy - 3) * (dy - 3) + (dx - 3) * (dx - 3);
        distS[i] = (d2 < 16) ? __expf(-(float)d2 * 0.0625f) : 0.0f;
    }

    // center intensities
    const size_t bBase = ((size_t)b * 32 + d) * 1024 + h * 32 + w0;
    float Ip[4];
    #pragma unroll
    for (int v = 0; v < 4; ++v) Ip[v] = batch[bBase + v];

    float wsum[4] = {0.f, 0.f, 0.f, 0.f};
    float acc[6][4] = {};

    for (int dz = 0; dz < 7; ++dz) {
        __syncthreads();              // previous-iteration readers done (also orders distS at dz=0)
        const int z = d + dz - 3;
        const bool zok = (z >= 0) && (z < 32);
        // stage padded batch slice
        {
            const float* src = batch + ((size_t)b * 32 + (zok ? z : 0)) * 1024;
            for (int i = tid; i < 38 * 38; i += 256) {
                int hp = i / 38, wp = i - hp * 38;
                int hh = hp - 3, ww = wp - 3;
                float val = EPSV;
                if (zok && (unsigned)hh < 32u && (unsigned)ww < 32u)
                    val = src[hh * 32 + ww];
                bS[hp * LS + wp] = val;
            }
        }
        // stage padded preds slices (6 classes)
        for (int i = tid; i < 6 * 38 * 38; i += 256) {
            int k = i / (38 * 38);
            int r = i - k * (38 * 38);
            int hp = r / 38, wp = r - hp * 38;
            int hh = hp - 3, ww = wp - 3;
            float val = EPSV;
            if (zok && (unsigned)hh < 32u && (unsigned)ww < 32u)
                val = preds[(((size_t)b * 6 + k) * 32 + z) * 1024 + hh * 32 + ww];
            pS[k * PLANE + hp * LS + wp] = val;
        }
        __syncthreads();

        const int gBase = dz * 49;
        for (int dy = 0; dy < 7; ++dy) {
            const int rowOff = (h + dy) * LS + w0;   // 16B-aligned
            const float4 b0 = *(const float4*)&bS[rowOff];
            const float4 b1 = *(const float4*)&bS[rowOff + 4];
            const float2 b2 = *(const float2*)&bS[rowOff + 8];
            float bseg[10] = {b0.x, b0.y, b0.z, b0.w, b1.x, b1.y, b1.z, b1.w, b2.x, b2.y};

            float g[7];
            #pragma unroll
            for (int dx = 0; dx < 7; ++dx) g[dx] = distS[gBase + dy * 7 + dx];  // broadcast reads

            float wv[7][4];
            #pragma unroll
            for (int dx = 0; dx < 7; ++dx) {
                #pragma unroll
                for (int v = 0; v < 4; ++v) {
                    float dI = Ip[v] - bseg[v + dx];
                    float e = __expf(dI * dI * -0.01f);   // sigmaI^2 = 100
                    float wgt = e * g[dx];
                    wv[dx][v] = wgt;
                    wsum[v] += wgt;
                }
            }
            #pragma unroll
            for (int k = 0; k < 6; ++k) {
                const int pOff = k * PLANE + rowOff;
                const float4 p0 = *(const float4*)&pS[pOff];
                const float4 p1 = *(const float4*)&pS[pOff + 4];
                const float2 p2 = *(const float2*)&pS[pOff + 8];
                float pseg[10] = {p0.x, p0.y, p0.z, p0.w, p1.x, p1.y, p1.z, p1.w, p2.x, p2.y};
                #pragma unroll
                for (int dx = 0; dx < 7; ++dx) {
                    #pragma unroll
                    for (int v = 0; v < 4; ++v)
                        acc[k][v] += wv[dx][v] * pseg[v + dx];
                }
            }
        }
    }

    // fold in center preds: A_k = sum_v acc*predC, V_k = sum_v wsum*predC
    float pA[6], pV[6];
    #pragma unroll
    for (int k = 0; k < 6; ++k) {
        const size_t pc = (((size_t)b * 6 + k) * 32 + d) * 1024 + h * 32 + w0;
        float a = 0.f, vv = 0.f;
        #pragma unroll
        for (int v = 0; v < 4; ++v) {
            float pcv = preds[pc + v];
            a += acc[k][v] * pcv;
            vv += wsum[v] * pcv;
        }
        pA[k] = a; pV[k] = vv;
    }

    // wave reduction (64 lanes)
    #pragma unroll
    for (int k = 0; k < 6; ++k) {
        #pragma unroll
        for (int off = 32; off > 0; off >>= 1) {
            pA[k] += __shfl_down(pA[k], off);
            pV[k] += __shfl_down(pV[k], off);
        }
    }
    const int lane = tid & 63, wave = tid >> 6;
    if (lane == 0) {
        #pragma unroll
        for (int k = 0; k < 6; ++k) {
            redBuf[wave][k] = pA[k];
            redBuf[wave][6 + k] = pV[k];
        }
    }
    __syncthreads();
    if (tid < 12) {
        float s = redBuf[0][tid] + redBuf[1][tid] + redBuf[2][tid] + redBuf[3][tid];
        if (tid < 6) wsA[blockIdx.x * 6 + tid] = s;
        else         wsV[blockIdx.x * 6 + (tid - 6)] = s;
    }
}

__global__ void ncut_final(const float* __restrict__ wsA, const float* __restrict__ wsV,
                           float* __restrict__ out) {
    __shared__ float ratio[8][6];
    const int t = threadIdx.x;
    if (t < 48) {
        int b = t / 6, k = t % 6;
        float sa = 0.f, sv = 0.f;
        for (int j = 0; j < 32; ++j) {
            sa += wsA[(b * 32 + j) * 6 + k];
            sv += wsV[(b * 32 + j) * 6 + k];
        }
        ratio[b][k] = sa / sv;
    }
    __syncthreads();
    if (t < 8) {
        float s = 0.f;
        #pragma unroll
        for (int k = 0; k < 6; ++k) s += ratio[t][k];
        out[t] = 6.0f - s;
    }
}

extern "C" void kernel_launch(void* const* d_in, const int* in_sizes, int n_in,
                              void* d_out, int out_size, void* d_ws, size_t ws_size,
                              hipStream_t stream) {
    const float* batch = (const float*)d_in[0];   // 8*1*32^3
    const float* preds = (const float*)d_in[1];   // 8*6*32^3
    float* out = (float*)d_out;                   // 8 floats
    float* wsA = (float*)d_ws;                    // 256*6 floats
    float* wsV = wsA + 256 * 6;                   // 256*6 floats

    ncut_main<<<256, 256, 0, stream>>>(batch, preds, wsA, wsV);
    ncut_final<<<1, 64, 0, stream>>>(wsA, wsV, out);
}

// Round 2
// 94.766 us; speedup vs baseline: 1.3748x; 1.3748x over previous
//
#include <hip/hip_runtime.h>
#include <hip/hip_bf16.h>

#define EPSV 2.220446049250313e-16f
// w = exp(-(dI^2)/100) * exp(-d2/16)  ==  exp2( dI^2 * C2 + d2 * C3 ),  0 if d2>=16
#define C2F (-0.014426950408889634f)   // -log2(e)/100
#define C3F (-0.09016844005555896f)    // -log2(e)/16

// batch: (8,1,32,32,32) f32 ; preds: (8,6,32,32,32) f32 ; out: (8,) f32
// PAD=3, WIN=7. Grid: (b,d,dz) = 8*32*7 = 1792 blocks, 256 threads.

__global__ __launch_bounds__(256) void ncut_main(const float* __restrict__ batch,
                                                 const float* __restrict__ preds,
                                                 float* __restrict__ wsA,
                                                 float* __restrict__ wsV) {
    constexpr int LS = 40;            // LDS row stride (floats): 160B, 16B-aligned
    constexpr int PLANE = 38 * LS;    // one padded (h,w) slice
    __shared__ float bS[PLANE];
    __shared__ float pS[6 * PLANE];
    __shared__ float glS[49];         // -log2e*d2/16 for this dz, -inf outside ball
    __shared__ float redBuf[4][12];

    const int tid = threadIdx.x;
    const int bx  = blockIdx.x;
    const int b   = bx / 224;         // 8 batches
    const int r   = bx - b * 224;
    const int d   = r / 7;            // 32 d-slices
    const int dz  = r - d * 7;        // 7 window z-offsets

    // spatial Gaussian (log2-domain) table for this dz
    if (tid < 49) {
        int dy = tid / 7, dx = tid - dy * 7;
        int d2 = (dz - 3) * (dz - 3) + (dy - 3) * (dy - 3) + (dx - 3) * (dx - 3);
        glS[tid] = (d2 < 16) ? (float)d2 * C3F : -__builtin_inff();
    }

    const int z = d + dz - 3;
    const bool zok = (z >= 0) && (z < 32);

    // stage padded batch slice for z
    {
        const float* src = batch + ((size_t)b * 32 + (zok ? z : 0)) * 1024;
        for (int i = tid; i < 38 * 38; i += 256) {
            int hp = i / 38, wp = i - hp * 38;
            int hh = hp - 3, ww = wp - 3;
            float val = EPSV;
            if (zok && (unsigned)hh < 32u && (unsigned)ww < 32u)
                val = src[hh * 32 + ww];
            bS[hp * LS + wp] = val;
        }
    }
    // stage padded preds slices (6 classes) for z
    for (int i = tid; i < 6 * 38 * 38; i += 256) {
        int k = i / 1444;
        int rr = i - k * 1444;
        int hp = rr / 38, wp = rr - hp * 38;
        int hh = hp - 3, ww = wp - 3;
        float val = EPSV;
        if (zok && (unsigned)hh < 32u && (unsigned)ww < 32u)
            val = preds[(((size_t)b * 6 + k) * 32 + z) * 1024 + hh * 32 + ww];
        pS[k * PLANE + hp * LS + wp] = val;
    }

    // center intensities (independent global loads, overlap with staging)
    const int h = tid >> 3;           // 0..31 (row)
    const int w0 = (tid & 7) << 2;    // 0,4,...,28 (4 voxels per thread)
    const size_t bBase = ((size_t)b * 32 + d) * 1024 + h * 32 + w0;
    float Ip[4];
    #pragma unroll
    for (int v = 0; v < 4; ++v) Ip[v] = batch[bBase + v];

    __syncthreads();

    float wsum[4] = {0.f, 0.f, 0.f, 0.f};
    float acc[6][4] = {};

    #pragma unroll
    for (int dy = 0; dy < 7; ++dy) {
        const int rowOff = (h + dy) * LS + w0;   // 16B-aligned
        const float4 b0 = *(const float4*)&bS[rowOff];
        const float4 b1 = *(const float4*)&bS[rowOff + 4];
        const float2 b2 = *(const float2*)&bS[rowOff + 8];
        float bseg[10] = {b0.x, b0.y, b0.z, b0.w, b1.x, b1.y, b1.z, b1.w, b2.x, b2.y};

        float g[7];
        #pragma unroll
        for (int dx = 0; dx < 7; ++dx) g[dx] = glS[dy * 7 + dx];  // broadcast reads

        float wv[7][4];
        #pragma unroll
        for (int dx = 0; dx < 7; ++dx) {
            #pragma unroll
            for (int v = 0; v < 4; ++v) {
                float dI = Ip[v] - bseg[v + dx];
                float wgt = __builtin_amdgcn_exp2f(__builtin_fmaf(dI * dI, C2F, g[dx]));
                wv[dx][v] = wgt;
                wsum[v] += wgt;
            }
        }
        #pragma unroll
        for (int k = 0; k < 6; ++k) {
            const int pOff = k * PLANE + rowOff;
            const float4 p0 = *(const float4*)&pS[pOff];
            const float4 p1 = *(const float4*)&pS[pOff + 4];
            const float2 p2 = *(const float2*)&pS[pOff + 8];
            float pseg[10] = {p0.x, p0.y, p0.z, p0.w, p1.x, p1.y, p1.z, p1.w, p2.x, p2.y};
            #pragma unroll
            for (int dx = 0; dx < 7; ++dx) {
                #pragma unroll
                for (int v = 0; v < 4; ++v)
                    acc[k][v] += wv[dx][v] * pseg[v + dx];
            }
        }
    }

    // fold in center preds: A_k = sum_v acc*predC, V_k = sum_v wsum*predC
    float pA[6], pV[6];
    #pragma unroll
    for (int k = 0; k < 6; ++k) {
        const size_t pc = (((size_t)b * 6 + k) * 32 + d) * 1024 + h * 32 + w0;
        float a = 0.f, vv = 0.f;
        #pragma unroll
        for (int v = 0; v < 4; ++v) {
            float pcv = preds[pc + v];
            a += acc[k][v] * pcv;
            vv += wsum[v] * pcv;
        }
        pA[k] = a; pV[k] = vv;
    }

    // wave reduction (64 lanes)
    #pragma unroll
    for (int k = 0; k < 6; ++k) {
        #pragma unroll
        for (int off = 32; off > 0; off >>= 1) {
            pA[k] += __shfl_down(pA[k], off);
            pV[k] += __shfl_down(pV[k], off);
        }
    }
    const int lane = tid & 63, wave = tid >> 6;
    if (lane == 0) {
        #pragma unroll
        for (int k = 0; k < 6; ++k) {
            redBuf[wave][k] = pA[k];
            redBuf[wave][6 + k] = pV[k];
        }
    }
    __syncthreads();
    if (tid < 12) {
        float s = redBuf[0][tid] + redBuf[1][tid] + redBuf[2][tid] + redBuf[3][tid];
        if (tid < 6) wsA[bx * 6 + tid] = s;
        else         wsV[bx * 6 + (tid - 6)] = s;
    }
}

// Reduce 224 partials per batch, form 6 - sum_k A_k/V_k
__global__ __launch_bounds__(256) void ncut_final(const float* __restrict__ wsA,
                                                  const float* __restrict__ wsV,
                                                  float* __restrict__ out) {
    __shared__ float redBuf[4][12];
    const int b = blockIdx.x;
    const int t = threadIdx.x;
    float a[6] = {}, v[6] = {};
    if (t < 224) {
        #pragma unroll
        for (int k = 0; k < 6; ++k) {
            a[k] = wsA[((size_t)b * 224 + t) * 6 + k];
            v[k] = wsV[((size_t)b * 224 + t) * 6 + k];
        }
    }
    #pragma unroll
    for (int k = 0; k < 6; ++k) {
        #pragma unroll
        for (int off = 32; off > 0; off >>= 1) {
            a[k] += __shfl_down(a[k], off);
            v[k] += __shfl_down(v[k], off);
        }
    }
    const int lane = t & 63, wave = t >> 6;
    if (lane == 0) {
        #pragma unroll
        for (int k = 0; k < 6; ++k) {
            redBuf[wave][k] = a[k];
            redBuf[wave][6 + k] = v[k];
        }
    }
    __syncthreads();
    if (t == 0) {
        float s = 0.f;
        #pragma unroll
        for (int k = 0; k < 6; ++k) {
            float sa = redBuf[0][k] + redBuf[1][k] + redBuf[2][k] + redBuf[3][k];
            float sv = redBuf[0][6 + k] + redBuf[1][6 + k] + redBuf[2][6 + k] + redBuf[3][6 + k];
            s += sa / sv;
        }
        out[b] = 6.0f - s;
    }
}

extern "C" void kernel_launch(void* const* d_in, const int* in_sizes, int n_in,
                              void* d_out, int out_size, void* d_ws, size_t ws_size,
                              hipStream_t stream) {
    const float* batch = (const float*)d_in[0];   // 8*1*32^3
    const float* preds = (const float*)d_in[1];   // 8*6*32^3
    float* out = (float*)d_out;                   // 8 floats
    float* wsA = (float*)d_ws;                    // 1792*6 floats
    float* wsV = wsA + 1792 * 6;                  // 1792*6 floats

    ncut_main<<<1792, 256, 0, stream>>>(batch, preds, wsA, wsV);
    ncut_final<<<8, 256, 0, stream>>>(wsA, wsV, out);
}

// Round 3
// 58.964 us; speedup vs baseline: 2.2095x; 1.6072x over previous
//
#include <hip/hip_runtime.h>
#include <hip/hip_bf16.h>

#define EPSV 2.220446049250313e-16f
// w = exp(-(dI^2)/100) * exp(-d2/16)  ==  exp2( dI^2 * C2 + d2 * C3 ),  0 if d2>=16
#define C2F (-0.014426950408889634f)   // -log2(e)/100
#define C3F (-0.09016844005555896f)    // -log2(e)/16

typedef float f2 __attribute__((ext_vector_type(2)));

// batch: (8,1,32,32,32) f32 ; preds: (8,6,32,32,32) f32 ; out: (8,) f32
// PAD=3, WIN=7. Grid: (b,d,dz) = 8*32*7 = 1792 blocks, 512 threads, 2 voxels/thread.

__global__ __launch_bounds__(512, 6) void ncut_main(const float* __restrict__ batch,
                                                    const float* __restrict__ preds,
                                                    float* __restrict__ wsA,
                                                    float* __restrict__ wsV) {
    constexpr int LS = 40;            // LDS row stride (floats)
    constexpr int PLANE = 38 * LS;    // one padded (h,w) slice
    __shared__ float bS[PLANE];
    __shared__ float pS[6 * PLANE];
    __shared__ float glS[49];         // d2*C3 for this dz, -inf outside ball
    __shared__ float redBuf[8][12];

    const int tid = threadIdx.x;
    const int bx  = blockIdx.x;
    const int b   = bx / 224;         // 8 batches
    const int r   = bx - b * 224;
    const int d   = r / 7;            // 32 d-slices
    const int dz  = r - d * 7;        // 7 window z-offsets

    if (tid < 49) {
        int dy = tid / 7, dx = tid - dy * 7;
        int d2 = (dz - 3) * (dz - 3) + (dy - 3) * (dy - 3) + (dx - 3) * (dx - 3);
        glS[tid] = (d2 < 16) ? (float)d2 * C3F : -__builtin_inff();
    }

    const int z = d + dz - 3;
    const bool zok = (z >= 0) && (z < 32);

    // stage padded batch slice for z
    {
        const float* src = batch + ((size_t)b * 32 + (zok ? z : 0)) * 1024;
        for (int i = tid; i < 38 * 38; i += 512) {
            int hp = i / 38, wp = i - hp * 38;
            int hh = hp - 3, ww = wp - 3;
            float val = EPSV;
            if (zok && (unsigned)hh < 32u && (unsigned)ww < 32u)
                val = src[hh * 32 + ww];
            bS[hp * LS + wp] = val;
        }
    }
    // stage padded preds slices (6 classes) for z
    for (int i = tid; i < 6 * 38 * 38; i += 512) {
        int k = i / 1444;
        int rr = i - k * 1444;
        int hp = rr / 38, wp = rr - hp * 38;
        int hh = hp - 3, ww = wp - 3;
        float val = EPSV;
        if (zok && (unsigned)hh < 32u && (unsigned)ww < 32u)
            val = preds[(((size_t)b * 6 + k) * 32 + z) * 1024 + hh * 32 + ww];
        pS[k * PLANE + hp * LS + wp] = val;
    }

    // center intensities (overlap with staging)
    const int h  = tid >> 4;          // 0..31 (row)
    const int w0 = (tid & 15) << 1;   // 0,2,...,30 (2 voxels per thread)
    const size_t bBase = ((size_t)b * 32 + d) * 1024 + h * 32 + w0;
    const f2 Ip2 = *(const f2*)&batch[bBase];

    __syncthreads();

    f2 wsum = {0.f, 0.f};
    f2 acc[6] = {};

    #pragma unroll
    for (int dy = 0; dy < 7; ++dy) {
        const int rowOff = (h + dy) * LS + w0;   // 8B-aligned
        float bseg[8];
        #pragma unroll
        for (int j = 0; j < 4; ++j) {
            f2 t = *(const f2*)&bS[rowOff + 2 * j];
            bseg[2 * j] = t.x; bseg[2 * j + 1] = t.y;
        }

        float g[7];
        #pragma unroll
        for (int dx = 0; dx < 7; ++dx) g[dx] = glS[dy * 7 + dx];  // broadcast reads

        f2 wv[7];
        #pragma unroll
        for (int dx = 0; dx < 7; ++dx) {
            f2 bv = {bseg[dx], bseg[dx + 1]};
            f2 dI = Ip2 - bv;
            f2 t  = dI * dI * C2F + (f2){g[dx], g[dx]};
            f2 w;
            w.x = __builtin_amdgcn_exp2f(t.x);
            w.y = __builtin_amdgcn_exp2f(t.y);
            wv[dx] = w;
            wsum += w;
        }
        #pragma unroll
        for (int k = 0; k < 6; ++k) {
            const int pOff = k * PLANE + rowOff;
            float pseg[8];
            #pragma unroll
            for (int j = 0; j < 4; ++j) {
                f2 t = *(const f2*)&pS[pOff + 2 * j];
                pseg[2 * j] = t.x; pseg[2 * j + 1] = t.y;
            }
            f2 a = acc[k];
            #pragma unroll
            for (int dx = 0; dx < 7; ++dx) {
                f2 pv = {pseg[dx], pseg[dx + 1]};
                a += wv[dx] * pv;
            }
            acc[k] = a;
        }
    }

    // fold in center preds: A_k = <acc, predC>, V_k = <wsum, predC>
    float pA[6], pV[6];
    #pragma unroll
    for (int k = 0; k < 6; ++k) {
        const size_t pc = (((size_t)b * 6 + k) * 32 + d) * 1024 + h * 32 + w0;
        f2 pcv = *(const f2*)&preds[pc];
        pA[k] = acc[k].x * pcv.x + acc[k].y * pcv.y;
        pV[k] = wsum.x * pcv.x + wsum.y * pcv.y;
    }

    // wave reduction (64 lanes)
    #pragma unroll
    for (int k = 0; k < 6; ++k) {
        #pragma unroll
        for (int off = 32; off > 0; off >>= 1) {
            pA[k] += __shfl_down(pA[k], off);
            pV[k] += __shfl_down(pV[k], off);
        }
    }
    const int lane = tid & 63, wave = tid >> 6;
    if (lane == 0) {
        #pragma unroll
        for (int k = 0; k < 6; ++k) {
            redBuf[wave][k] = pA[k];
            redBuf[wave][6 + k] = pV[k];
        }
    }
    __syncthreads();
    if (tid < 12) {
        float s = 0.f;
        #pragma unroll
        for (int wv8 = 0; wv8 < 8; ++wv8) s += redBuf[wv8][tid];
        if (tid < 6) wsA[bx * 6 + tid] = s;
        else         wsV[bx * 6 + (tid - 6)] = s;
    }
}

// Reduce 224 partials per batch, form 6 - sum_k A_k/V_k
__global__ __launch_bounds__(256) void ncut_final(const float* __restrict__ wsA,
                                                  const float* __restrict__ wsV,
                                                  float* __restrict__ out) {
    __shared__ float redBuf[4][12];
    const int b = blockIdx.x;
    const int t = threadIdx.x;
    float a[6] = {}, v[6] = {};
    if (t < 224) {
        #pragma unroll
        for (int k = 0; k < 6; ++k) {
            a[k] = wsA[((size_t)b * 224 + t) * 6 + k];
            v[k] = wsV[((size_t)b * 224 + t) * 6 + k];
        }
    }
    #pragma unroll
    for (int k = 0; k < 6; ++k) {
        #pragma unroll
        for (int off = 32; off > 0; off >>= 1) {
            a[k] += __shfl_down(a[k], off);
            v[k] += __shfl_down(v[k], off);
        }
    }
    const int lane = t & 63, wave = t >> 6;
    if (lane == 0) {
        #pragma unroll
        for (int k = 0; k < 6; ++k) {
            redBuf[wave][k] = a[k];
            redBuf[wave][6 + k] = v[k];
        }
    }
    __syncthreads();
    if (t == 0) {
        float s = 0.f;
        #pragma unroll
        for (int k = 0; k < 6; ++k) {
            float sa = redBuf[0][k] + redBuf[1][k] + redBuf[2][k] + redBuf[3][k];
            float sv = redBuf[0][6 + k] + redBuf[1][6 + k] + redBuf[2][6 + k] + redBuf[3][6 + k];
            s += sa / sv;
        }
        out[b] = 6.0f - s;
    }
}

extern "C" void kernel_launch(void* const* d_in, const int* in_sizes, int n_in,
                              void* d_out, int out_size, void* d_ws, size_t ws_size,
                              hipStream_t stream) {
    const float* batch = (const float*)d_in[0];   // 8*1*32^3
    const float* preds = (const float*)d_in[1];   // 8*6*32^3
    float* out = (float*)d_out;                   // 8 floats
    float* wsA = (float*)d_ws;                    // 1792*6 floats
    float* wsV = wsA + 1792 * 6;                  // 1792*6 floats

    ncut_main<<<1792, 512, 0, stream>>>(batch, preds, wsA, wsV);
    ncut_final<<<8, 256, 0, stream>>>(wsA, wsV, out);
}

// Round 4
// 49.272 us; speedup vs baseline: 2.6442x; 1.1967x over previous
//
#include <hip/hip_runtime.h>

#define EPSV 2.220446049250313e-16f
#define C3F  (-0.09016844005555896f)   // -log2(e)/16
#define SSCL 0.1201122408786449f       // sqrt(log2(e)/100); (SSCL*dI)^2 = dI^2*log2(e)/100

typedef float f2 __attribute__((ext_vector_type(2)));
typedef float f4 __attribute__((ext_vector_type(4)));

// batch: (8,1,32,32,32) f32 ; preds: (8,6,32,32,32) f32 ; out: (8,) f32
// PAD=3, WIN=7. w(p,off) = exp(-(dI)^2/100)*exp(-d2/16) = exp2(g - (s*dI)^2), g = -d2*log2e/16 (-inf outside ball)
// Grid: (b,d,dz) = 8*32*7 = 1792 blocks, 512 threads, 2 voxels (w-pair) per thread.

__global__ __launch_bounds__(512) void ncut_main(const float* __restrict__ batch,
                                                 const float* __restrict__ preds,
                                                 float* __restrict__ wsA,
                                                 float* __restrict__ wsV) {
    constexpr int LS = 40;             // LDS row stride (floats)
    constexpr int PLANE = 38 * LS;     // 1520 floats per padded slice
    __shared__ float sAll[7 * PLANE];  // plane 0: scaled batch; planes 1..6: preds
    __shared__ float glS[49];          // g(dy,dx) for this dz; -inf outside ball
    __shared__ float redBuf[8][12];

    const int tid = threadIdx.x;
    const int bx  = blockIdx.x;
    const int b   = bx / 224;          // 8 batches
    const int r   = bx - b * 224;
    const int d   = r / 7;             // 32 d-slices
    const int dz  = r - d * 7;         // 7 window z-offsets

    if (tid < 49) {
        int dy = tid / 7, dx = tid - dy * 7;
        int d2 = (dz - 3) * (dz - 3) + (dy - 3) * (dy - 3) + (dx - 3) * (dx - 3);
        glS[tid] = (d2 < 16) ? (float)d2 * C3F : -__builtin_inff();
    }

    const int z = d + dz - 3;
    const bool zok = (z >= 0) && (z < 32);

    // ---- init all planes to pad value (aligned f4 stores, pow2 addressing) ----
    {
        f4* b4 = (f4*)sAll;                    // 380 f4 (batch plane, scaled pad)
        const f4 bpad = {EPSV * SSCL, EPSV * SSCL, EPSV * SSCL, EPSV * SSCL};
        if (tid < 380) b4[tid] = bpad;
        f4* p4 = (f4*)(sAll + PLANE);          // 2280 f4 (pred planes)
        const f4 ppad = {EPSV, EPSV, EPSV, EPSV};
        for (int i = tid; i < 2280; i += 512) p4[i] = ppad;
    }
    __syncthreads();

    // ---- copy interiors: coalesced f4 global loads, shifts/masks only ----
    if (zok) {
        const float* bsrc = batch + ((size_t)b * 32 + z) * 1024;
        const float* psrc = preds + ((size_t)b * 6 * 32 + z) * 1024;   // + k*32768
        #pragma unroll
        for (int it = 0; it < 4; ++it) {
            int idx = tid + it * 512;          // 0..1791 = 7 planes * 256 f4-tiles
            if (idx < 1792) {
                int p  = idx >> 8;             // 0..6
                int r8 = idx & 255;
                int hh = r8 >> 3;              // 0..31
                int j4 = (r8 & 7) << 2;        // 0,4,...,28
                const float* src = (p == 0) ? (bsrc + hh * 32 + j4)
                                            : (psrc + (size_t)(p - 1) * 32768 + hh * 32 + j4);
                f4 v = *(const f4*)src;
                if (p == 0) v *= SSCL;
                float* dst = sAll + p * PLANE + (hh + 3) * LS + (j4 + 3);
                dst[0] = v.x; dst[1] = v.y; dst[2] = v.z; dst[3] = v.w;
            }
        }
    }

    // center intensities (pre-scaled), overlap with staging
    const int h  = tid >> 4;           // 0..31 (row)
    const int w0 = (tid & 15) << 1;    // 0,2,...,30 (2 voxels per thread)
    const size_t bBase = ((size_t)b * 32 + d) * 1024 + h * 32 + w0;
    f2 Ip2 = *(const f2*)&batch[bBase];
    Ip2 *= SSCL;

    __syncthreads();

    f2 wsum = {0.f, 0.f};
    f2 acc[6] = {};

    #pragma unroll
    for (int dy = 0; dy < 7; ++dy) {
        const int rowOff = (h + dy) * LS + w0;     // 8B-aligned
        const float* brow = sAll + rowOff;
        float bseg[8];
        #pragma unroll
        for (int j = 0; j < 4; ++j) {
            f2 t = *(const f2*)(brow + 2 * j);
            bseg[2 * j] = t.x; bseg[2 * j + 1] = t.y;
        }

        float g[7];
        #pragma unroll
        for (int dx = 0; dx < 7; ++dx) g[dx] = glS[dy * 7 + dx];   // uniform broadcast

        f2 wv[7];
        #pragma unroll
        for (int dx = 0; dx < 7; ++dx) {
            f2 bv = {bseg[dx], bseg[dx + 1]};
            f2 dI = Ip2 - bv;
            f2 t  = (f2){g[dx], g[dx]} - dI * dI;   // single pk_fma (neg modifier)
            f2 w;
            w.x = __builtin_amdgcn_exp2f(t.x);
            w.y = __builtin_amdgcn_exp2f(t.y);
            wv[dx] = w;
            wsum += w;
        }
        #pragma unroll
        for (int k = 0; k < 6; ++k) {
            const float* prow = sAll + (k + 1) * PLANE + rowOff;
            float pseg[8];
            #pragma unroll
            for (int j = 0; j < 4; ++j) {
                f2 t = *(const f2*)(prow + 2 * j);
                pseg[2 * j] = t.x; pseg[2 * j + 1] = t.y;
            }
            f2 a = acc[k];
            #pragma unroll
            for (int dx = 0; dx < 7; ++dx)
                a += wv[dx] * (f2){pseg[dx], pseg[dx + 1]};
            acc[k] = a;
        }
    }

    // fold in center preds: A_k = <acc, predC>, V_k = <wsum, predC>
    float pA[6], pV[6];
    #pragma unroll
    for (int k = 0; k < 6; ++k) {
        const size_t pc = (((size_t)b * 6 + k) * 32 + d) * 1024 + h * 32 + w0;
        f2 pcv = *(const f2*)&preds[pc];
        pA[k] = acc[k].x * pcv.x + acc[k].y * pcv.y;
        pV[k] = wsum.x * pcv.x + wsum.y * pcv.y;
    }

    // wave reduction (64 lanes)
    #pragma unroll
    for (int k = 0; k < 6; ++k) {
        #pragma unroll
        for (int off = 32; off > 0; off >>= 1) {
            pA[k] += __shfl_down(pA[k], off);
            pV[k] += __shfl_down(pV[k], off);
        }
    }
    const int lane = tid & 63, wave = tid >> 6;
    if (lane == 0) {
        #pragma unroll
        for (int k = 0; k < 6; ++k) {
            redBuf[wave][k] = pA[k];
            redBuf[wave][6 + k] = pV[k];
        }
    }
    __syncthreads();
    if (tid < 12) {
        float s = 0.f;
        #pragma unroll
        for (int wv8 = 0; wv8 < 8; ++wv8) s += redBuf[wv8][tid];
        if (tid < 6) wsA[bx * 6 + tid] = s;
        else         wsV[bx * 6 + (tid - 6)] = s;
    }
}

// Reduce 224 partials per batch, form 6 - sum_k A_k/V_k
__global__ __launch_bounds__(256) void ncut_final(const float* __restrict__ wsA,
                                                  const float* __restrict__ wsV,
                                                  float* __restrict__ out) {
    __shared__ float redBuf[4][12];
    const int b = blockIdx.x;
    const int t = threadIdx.x;
    float a[6] = {}, v[6] = {};
    if (t < 224) {
        #pragma unroll
        for (int k = 0; k < 6; ++k) {
            a[k] = wsA[((size_t)b * 224 + t) * 6 + k];
            v[k] = wsV[((size_t)b * 224 + t) * 6 + k];
        }
    }
    #pragma unroll
    for (int k = 0; k < 6; ++k) {
        #pragma unroll
        for (int off = 32; off > 0; off >>= 1) {
            a[k] += __shfl_down(a[k], off);
            v[k] += __shfl_down(v[k], off);
        }
    }
    const int lane = t & 63, wave = t >> 6;
    if (lane == 0) {
        #pragma unroll
        for (int k = 0; k < 6; ++k) {
            redBuf[wave][k] = a[k];
            redBuf[wave][6 + k] = v[k];
        }
    }
    __syncthreads();
    if (t == 0) {
        float s = 0.f;
        #pragma unroll
        for (int k = 0; k < 6; ++k) {
            float sa = redBuf[0][k] + redBuf[1][k] + redBuf[2][k] + redBuf[3][k];
            float sv = redBuf[0][6 + k] + redBuf[1][6 + k] + redBuf[2][6 + k] + redBuf[3][6 + k];
            s += sa / sv;
        }
        out[b] = 6.0f - s;
    }
}

extern "C" void kernel_launch(void* const* d_in, const int* in_sizes, int n_in,
                              void* d_out, int out_size, void* d_ws, size_t ws_size,
                              hipStream_t stream) {
    const float* batch = (const float*)d_in[0];   // 8*1*32^3
    const float* preds = (const float*)d_in[1];   // 8*6*32^3
    float* out = (float*)d_out;                   // 8 floats
    float* wsA = (float*)d_ws;                    // 1792*6 floats
    float* wsV = wsA + 1792 * 6;                  // 1792*6 floats

    ncut_main<<<1792, 512, 0, stream>>>(batch, preds, wsA, wsV);
    ncut_final<<<8, 256, 0, stream>>>(wsA, wsV, out);
}

// Round 5
// 42.851 us; speedup vs baseline: 3.0404x; 1.1498x over previous
//
#include <hip/hip_runtime.h>

#define EPSV 2.220446049250313e-16f
#define C3F  (-0.09016844005555896f)   // -log2(e)/16
#define SSCL 0.1201122408786449f       // sqrt(log2(e)/100); (SSCL*dI)^2 = dI^2*log2(e)/100

typedef float f2 __attribute__((ext_vector_type(2)));
typedef float f4 __attribute__((ext_vector_type(4)));

// batch: (8,1,32,32,32) f32 ; preds: (8,6,32,32,32) f32 ; out: (8,) f32
// PAD=3, WIN=7. w(p,off) = exp2(g - (s*dI)^2), g = -d2*log2e/16, zero outside ball d2<16.
// Grid: (b,d,dz) = 8*32*7 = 1792 blocks, 256 threads, 4 voxels (w-quad) per thread.

__global__ __launch_bounds__(256) void ncut_main(const float* __restrict__ batch,
                                                 const float* __restrict__ preds,
                                                 float* __restrict__ wsA,
                                                 float* __restrict__ wsV) {
    constexpr int LS = 40;             // LDS row stride (floats)
    constexpr int PLANE = 38 * LS;     // 1520 floats per padded slice
    __shared__ float sAll[7 * PLANE];  // plane 0: scaled batch; planes 1..6: preds
    __shared__ float redBuf[4][12];

    const int tid = threadIdx.x;
    const int bx  = blockIdx.x;
    const int b   = bx / 224;          // 8 batches
    const int r   = bx - b * 224;
    const int d   = r / 7;             // 32 d-slices
    const int dz  = r - d * 7;         // 7 window z-offsets

    const int z = d + dz - 3;
    const bool zok = (z >= 0) && (z < 32);

    // ---- init all planes to pad value (aligned f4 stores) ----
    {
        f4* b4 = (f4*)sAll;                    // 380 f4 (batch plane, scaled pad)
        const f4 bpad = {EPSV * SSCL, EPSV * SSCL, EPSV * SSCL, EPSV * SSCL};
        for (int i = tid; i < 380; i += 256) b4[i] = bpad;
        f4* p4 = (f4*)(sAll + PLANE);          // 2280 f4 (pred planes)
        const f4 ppad = {EPSV, EPSV, EPSV, EPSV};
        for (int i = tid; i < 2280; i += 256) p4[i] = ppad;
    }
    __syncthreads();

    // ---- copy interiors: one plane per iteration, fully coalesced f4 ----
    const int hh = tid >> 3;           // 0..31
    const int j4 = (tid & 7) << 2;     // 0,4,...,28
    if (zok) {
        const float* bsrc = batch + ((size_t)b * 32 + z) * 1024 + hh * 32 + j4;
        const float* psrc = preds + ((size_t)b * 6 * 32 + z) * 1024 + hh * 32 + j4;
        {
            f4 v = *(const f4*)bsrc;
            v *= SSCL;
            float* dst = sAll + (hh + 3) * LS + (j4 + 3);
            dst[0] = v.x; dst[1] = v.y; dst[2] = v.z; dst[3] = v.w;
        }
        #pragma unroll
        for (int p = 0; p < 6; ++p) {
            f4 v = *(const f4*)(psrc + (size_t)p * 32768);
            float* dst = sAll + (p + 1) * PLANE + (hh + 3) * LS + (j4 + 3);
            dst[0] = v.x; dst[1] = v.y; dst[2] = v.z; dst[3] = v.w;
        }
    }

    // center intensities (pre-scaled), overlap with staging
    const int h  = hh;                 // 0..31 (row)
    const int w0 = j4;                 // 0,4,...,28 (4 voxels per thread)
    f4 Ip = *(const f4*)&batch[((size_t)b * 32 + d) * 1024 + h * 32 + w0];
    Ip *= SSCL;

    __syncthreads();

    f4 wsum = {};
    f4 acc[6] = {};
    const int czz = (dz - 3) * (dz - 3);          // scalar (from blockIdx)
    const float gz = (float)czz * C3F;            // scalar

    #pragma unroll
    for (int dy = 0; dy < 7; ++dy) {
        const int cyy = (dy - 3) * (dy - 3);      // compile-time
        if (czz + cyy >= 16) continue;            // scalar-uniform: whole row outside ball

        const int rowOff = (h + dy) * LS + w0;    // 16B-aligned
        const float* brow = sAll + rowOff;
        f4 bA = *(const f4*)brow;
        f4 bB = *(const f4*)(brow + 4);
        f2 bC = *(const f2*)(brow + 8);
        float bseg[10] = {bA.x, bA.y, bA.z, bA.w, bB.x, bB.y, bB.z, bB.w, bC.x, bC.y};

        f4 wv[7];
        #pragma unroll
        for (int dx = 0; dx < 7; ++dx) {
            const int cxx = (dx - 3) * (dx - 3);  // compile-time
            f4 w = {};
            if (czz + cyy + cxx < 16) {           // scalar-uniform branch, no exec mask
                const float g = gz + (float)(cyy + cxx) * C3F;
                f4 bv = {bseg[dx], bseg[dx + 1], bseg[dx + 2], bseg[dx + 3]};
                f4 dI = Ip - bv;
                f4 t  = (f4){g, g, g, g} - dI * dI;   // pk_fma with neg modifier
                w.x = __builtin_amdgcn_exp2f(t.x);
                w.y = __builtin_amdgcn_exp2f(t.y);
                w.z = __builtin_amdgcn_exp2f(t.z);
                w.w = __builtin_amdgcn_exp2f(t.w);
                wsum += w;
            }
            wv[dx] = w;
        }

        #pragma unroll
        for (int k = 0; k < 6; ++k) {             // branch-free FMA block
            const float* prow = sAll + (k + 1) * PLANE + rowOff;
            f4 qA = *(const f4*)prow;
            f4 qB = *(const f4*)(prow + 4);
            f2 qC = *(const f2*)(prow + 8);
            float pseg[10] = {qA.x, qA.y, qA.z, qA.w, qB.x, qB.y, qB.z, qB.w, qC.x, qC.y};
            f4 a = acc[k];
            #pragma unroll
            for (int dx = 0; dx < 7; ++dx)
                a += wv[dx] * (f4){pseg[dx], pseg[dx + 1], pseg[dx + 2], pseg[dx + 3]};
            acc[k] = a;
        }
    }

    // fold in center preds: A_k = <acc_k, predC_k>, V_k = <wsum, predC_k>
    float pA[6], pV[6];
    #pragma unroll
    for (int k = 0; k < 6; ++k) {
        const size_t pc = (((size_t)b * 6 + k) * 32 + d) * 1024 + h * 32 + w0;
        f4 pcv = *(const f4*)&preds[pc];
        pA[k] = acc[k].x * pcv.x + acc[k].y * pcv.y + acc[k].z * pcv.z + acc[k].w * pcv.w;
        pV[k] = wsum.x * pcv.x + wsum.y * pcv.y + wsum.z * pcv.z + wsum.w * pcv.w;
    }

    // wave reduction (64 lanes)
    #pragma unroll
    for (int k = 0; k < 6; ++k) {
        #pragma unroll
        for (int off = 32; off > 0; off >>= 1) {
            pA[k] += __shfl_down(pA[k], off);
            pV[k] += __shfl_down(pV[k], off);
        }
    }
    const int lane = tid & 63, wave = tid >> 6;
    if (lane == 0) {
        #pragma unroll
        for (int k = 0; k < 6; ++k) {
            redBuf[wave][k] = pA[k];
            redBuf[wave][6 + k] = pV[k];
        }
    }
    __syncthreads();
    if (tid < 12) {
        float s = redBuf[0][tid] + redBuf[1][tid] + redBuf[2][tid] + redBuf[3][tid];
        if (tid < 6) wsA[bx * 6 + tid] = s;
        else         wsV[bx * 6 + (tid - 6)] = s;
    }
}

// Reduce 224 partials per batch, form 6 - sum_k A_k/V_k
__global__ __launch_bounds__(256) void ncut_final(const float* __restrict__ wsA,
                                                  const float* __restrict__ wsV,
                                                  float* __restrict__ out) {
    __shared__ float redBuf[4][12];
    const int b = blockIdx.x;
    const int t = threadIdx.x;
    float a[6] = {}, v[6] = {};
    if (t < 224) {
        #pragma unroll
        for (int k = 0; k < 6; ++k) {
            a[k] = wsA[((size_t)b * 224 + t) * 6 + k];
            v[k] = wsV[((size_t)b * 224 + t) * 6 + k];
        }
    }
    #pragma unroll
    for (int k = 0; k < 6; ++k) {
        #pragma unroll
        for (int off = 32; off > 0; off >>= 1) {
            a[k] += __shfl_down(a[k], off);
            v[k] += __shfl_down(v[k], off);
        }
    }
    const int lane = t & 63, wave = t >> 6;
    if (lane == 0) {
        #pragma unroll
        for (int k = 0; k < 6; ++k) {
            redBuf[wave][k] = a[k];
            redBuf[wave][6 + k] = v[k];
        }
    }
    __syncthreads();
    if (t == 0) {
        float s = 0.f;
        #pragma unroll
        for (int k = 0; k < 6; ++k) {
            float sa = redBuf[0][k] + redBuf[1][k] + redBuf[2][k] + redBuf[3][k];
            float sv = redBuf[0][6 + k] + redBuf[1][6 + k] + redBuf[2][6 + k] + redBuf[3][6 + k];
            s += sa / sv;
        }
        out[b] = 6.0f - s;
    }
}

extern "C" void kernel_launch(void* const* d_in, const int* in_sizes, int n_in,
                              void* d_out, int out_size, void* d_ws, size_t ws_size,
                              hipStream_t stream) {
    const float* batch = (const float*)d_in[0];   // 8*1*32^3
    const float* preds = (const float*)d_in[1];   // 8*6*32^3
    float* out = (float*)d_out;                   // 8 floats
    float* wsA = (float*)d_ws;                    // 1792*6 floats
    float* wsV = wsA + 1792 * 6;                  // 1792*6 floats

    ncut_main<<<1792, 256, 0, stream>>>(batch, preds, wsA, wsV);
    ncut_final<<<8, 256, 0, stream>>>(wsA, wsV, out);
}